// Round 14
// baseline (31.176 us; speedup 1.0000x reference)
//
#include <hip/hip_runtime.h>
#include <math.h>

#define NV 65536
#define NE 4096
#define NP 4096
#define NT 512
#define NB 32              // y-buckets
#define CAP 4096           // per-bucket capacity; cnt <= NE always
#define SENTF 1000000000.0f
#define BIGF 1e30f

// ---------------- wave(64) reduction helpers ----------------
__device__ __forceinline__ float waveMinF(float v) {
    #pragma unroll
    for (int o = 32; o; o >>= 1) v = fminf(v, __shfl_xor(v, o, 64));
    return v;
}
__device__ __forceinline__ float waveMaxF(float v) {
    #pragma unroll
    for (int o = 32; o; o >>= 1) v = fmaxf(v, __shfl_xor(v, o, 64));
    return v;
}
__device__ __forceinline__ int waveSumI(int v) {
    #pragma unroll
    for (int o = 32; o; o >>= 1) v += __shfl_xor(v, o, 64);
    return v;
}
__device__ __forceinline__ int waveMinI(int v) {
    #pragma unroll
    for (int o = 32; o; o >>= 1) v = min(v, __shfl_xor(v, o, 64));
    return v;
}

// ---------------- kernel 1: buckets (0..31) + pk2/ea/eb (32..35) + table (36) ----------------
// R13-validated: atomic-free ordered compaction per bucket block.
__global__ __launch_bounds__(1024) void prep_kernel(
        const float* __restrict__ verts,
        const int*   __restrict__ edges,
        const float* __restrict__ tab,
        float2* __restrict__ pk2, float* __restrict__ ea, float* __restrict__ eb,
        float4* __restrict__ tb4,
        float4* __restrict__ bk4, int* __restrict__ cnt) {
    const int blk = blockIdx.x;
    const int tid = threadIdx.x;

    if (blk < NB) {
        __shared__ int sWT[16];
        const int lane = tid & 63;
        const int wv   = tid >> 6;

        float4 rec[4];
        int    flg[4];
        int    c = 0;
        #pragma unroll
        for (int j = 0; j < 4; ++j) {
            int e  = tid * 4 + j;
            int i0 = edges[2 * e + 0];
            int i1 = edges[2 * e + 1];
            float x0 = verts[3 * i0 + 0], y0 = verts[3 * i0 + 1];
            float x1 = verts[3 * i1 + 0], y1 = verts[3 * i1 + 1];
            float a = (y0 - y1) / (x0 - x1);
            float b = y0 - a * x0;
            float ymn = fminf(y0, y1), ymx = fmaxf(y0, y1);
            rec[j] = make_float4(ymn, ymx, 1.0f / a, b);   // validated phase-2 record
            int b0 = (int)fminf(fmaxf(ymn * (float)NB, 0.f), (float)(NB - 1));
            int b1 = (int)fminf(fmaxf(ymx * (float)NB, 0.f), (float)(NB - 1));
            flg[j] = (blk >= b0) && (blk <= b1);
            c += flg[j];
        }
        int inc = c;
        #pragma unroll
        for (int o = 1; o < 64; o <<= 1) {
            int u = __shfl_up(inc, o, 64);
            if (lane >= o) inc += u;
        }
        if (lane == 63) sWT[wv] = inc;
        __syncthreads();
        int base = 0;
        for (int i = 0; i < wv; ++i) base += sWT[i];
        int off = base + inc - c;
        float4* dst = bk4 + (size_t)blk * CAP;
        #pragma unroll
        for (int j = 0; j < 4; ++j)
            if (flg[j]) dst[off++] = rec[j];
        if (tid == 0) {
            int tot = 0;
            for (int i = 0; i < 16; ++i) tot += sWT[i];
            cnt[blk] = tot;
        }
    } else if (blk < NB + 4) {
        int e  = (blk - NB) * 1024 + tid;
        int i0 = edges[2 * e + 0];
        int i1 = edges[2 * e + 1];
        float x0 = verts[3 * i0 + 0], y0 = verts[3 * i0 + 1];
        float x1 = verts[3 * i1 + 0], y1 = verts[3 * i1 + 1];
        float a = (y0 - y1) / (x0 - x1);
        float b = y0 - a * x0;
        pk2[e] = make_float2(fminf(x0, x1), fmaxf(x0, x1));   // phase-1 record
        ea[e] = a; eb[e] = b;
    } else {
        if (tid < NT) {
            const float* r = tab + 7 * tid;
            tb4[tid] = make_float4(r[3], r[4], r[5], r[6]);
        }
    }
}

// ---------------- kernel 2: 4 independent waves/block ----------------
// Phase 1: 1024-edge vote rounds (16 edges/lane, 8 independent float4 loads
// of (xmn,xmx) pairs) -> worst-case tail 4 pipelined rounds, not 64 serial.
// Phase 2: bucket-pruned (R9/R13-validated body).
__global__ __launch_bounds__(256) void point_kernel(
        const float*  __restrict__ verts,
        const int*    __restrict__ listAll,
        const float2* __restrict__ pk2,
        const float*  __restrict__ ea, const float* __restrict__ eb,
        const float4* __restrict__ bk4, const int* __restrict__ cnt,
        const float4* __restrict__ tb4,
        float* __restrict__ mOut, int* __restrict__ vOut) {
    const int lane = threadIdx.x & 63;
    const int w    = threadIdx.x >> 6;
    const int p    = blockIdx.x * 4 + w;

    int   vi = listAll[p];
    float px = verts[3 * vi + 0];
    float py = verts[3 * vi + 1];

    // ---- phase 1: first edge with px strictly inside (xmn, xmx) ----
    const float4* pk2v = (const float4*)pk2;   // one float4 = edges (2k, 2k+1)
    int idxSel = NE;
    for (int r = 0; r < NE / 1024; ++r) {
        const int ebase = r * 1024 + lane * 16;   // my 16 consecutive edges
        const int vb    = ebase >> 1;             // float4 index (8 per lane)
        float4 q0 = pk2v[vb + 0], q1 = pk2v[vb + 1];
        float4 q2 = pk2v[vb + 2], q3 = pk2v[vb + 3];
        float4 q4 = pk2v[vb + 4], q5 = pk2v[vb + 5];
        float4 q6 = pk2v[vb + 6], q7 = pk2v[vb + 7];
        int il = NE;
        // descending edge order: lowest index overwrites last -> lane-local argmax(condA)
        if ((px > q7.z) && (px < q7.w)) il = ebase + 15;
        if ((px > q7.x) && (px < q7.y)) il = ebase + 14;
        if ((px > q6.z) && (px < q6.w)) il = ebase + 13;
        if ((px > q6.x) && (px < q6.y)) il = ebase + 12;
        if ((px > q5.z) && (px < q5.w)) il = ebase + 11;
        if ((px > q5.x) && (px < q5.y)) il = ebase + 10;
        if ((px > q4.z) && (px < q4.w)) il = ebase + 9;
        if ((px > q4.x) && (px < q4.y)) il = ebase + 8;
        if ((px > q3.z) && (px < q3.w)) il = ebase + 7;
        if ((px > q3.x) && (px < q3.y)) il = ebase + 6;
        if ((px > q2.z) && (px < q2.w)) il = ebase + 5;
        if ((px > q2.x) && (px < q2.y)) il = ebase + 4;
        if ((px > q1.z) && (px < q1.w)) il = ebase + 3;
        if ((px > q1.x) && (px < q1.y)) il = ebase + 2;
        if ((px > q0.z) && (px < q0.w)) il = ebase + 1;
        if ((px > q0.x) && (px < q0.y)) il = ebase + 0;
        if (il < NE) idxSel = il;
        if (__any(il < NE)) break;   // first round with a hit contains the global first hit
    }
    int mi  = waveMinI(idxSel);
    int idx = (mi >= NE) ? (NE - 1) : mi;      // wave-uniform
    float a_ = ea[idx], b_ = eb[idx];          // R2-validated winner fetch

    float exposeY = a_ * px + b_;              // identical arithmetic to reference
    float L1 = fabsf(py - exposeY);
    float cy = 0.5f * (py + exposeY);
    float cx = px;

    // ---- phase 2: scan only bucket(cy) (R9/R13-validated body) ----
    float kf = fminf(fmaxf(cy * (float)NB, 0.f), (float)(NB - 1));  // NaN-safe clamp
    int   k  = (int)kf;
    int   len = cnt[k];
    const float4* bl = bk4 + (size_t)k * CAP;

    int   nAcc = 0, hasS = 0, hasI = 0;
    float xallmx = -SENTF, xallmn = SENTF;
    float xs = SENTF, xinf = -SENTF;
    for (int i = lane; i < len; i += 64) {
        float4 q = bl[i];                  // (ymn, ymx, 1/a, b)
        bool  c  = (cy > q.x) && (cy < q.y);
        float xi = (cy - q.w) * q.z;       // identical arithmetic to validated path
        nAcc += c ? 1 : 0;
        xallmx = fmaxf(xallmx, c ? xi : -SENTF);
        xallmn = fminf(xallmn, c ? xi :  SENTF);
        bool sp  = c && (xi >= cx);
        bool in_ = c && (xi <  cx);
        xs   = fminf(xs,   sp  ? xi :  SENTF);
        xinf = fmaxf(xinf, in_ ? xi : -SENTF);
        hasS |= sp ? 1 : 0;
        hasI |= in_ ? 1 : 0;
    }
    int packed = nAcc | (hasS << 16) | (hasI << 24);
    packed = waveSumI(packed);
    xallmx = waveMaxF(xallmx);
    xallmn = waveMinF(xallmn);
    xs     = waveMinF(xs);
    xinf   = waveMaxF(xinf);
    int n  = packed & 0xFFFF;
    int hS = (packed >> 16) & 0xFF;
    int hI = (packed >> 24) & 0xFF;

    bool valid = (n == 2) || ((n > 2) && (hS > 0) && (hI > 0));
    float dx = (n == 2) ? (xallmx - xallmn) : (xs - xinf);
    float L2 = fabsf(dx);
    float d1 = fabsf(cy - 1.0f);
    float d2 = fabsf(px - 1.0f);

    // ---- table min (validated float4 path) ----
    float pm = INFINITY;
    #pragma unroll
    for (int kk = 0; kk < NT / 64; ++kk) {
        float4 r = tb4[kk * 64 + lane];
        float al = fabsf(L1 - r.x) + fabsf(L2 - r.y) +
                   fabsf(d1 - r.z) + fabsf(d2 - r.w);
        pm = fminf(pm, al);
    }
    pm = waveMinF(pm);

    if (lane == 0) {
        mOut[p] = valid ? pm : BIGF;
        vOut[p] = valid ? 1 : 0;
    }
}

// ---------------- kernel 3: cummin + masked sum (validated) ----------------
__global__ __launch_bounds__(1024) void scan_kernel(const float* __restrict__ m,
                                                    const int*   __restrict__ valid,
                                                    float* __restrict__ out) {
    __shared__ float wAgg[16];
    __shared__ float wSum[16];
    int t = threadIdx.x;
    int lane = t & 63, wid = t >> 6;

    float v[4]; int vl[4];
    #pragma unroll
    for (int j = 0; j < 4; j++) { v[j] = m[4 * t + j]; vl[j] = valid[4 * t + j]; }
    float cmin = fminf(fminf(v[0], v[1]), fminf(v[2], v[3]));

    float inc = cmin;
    #pragma unroll
    for (int o = 1; o < 64; o <<= 1) {
        float u = __shfl_up(inc, o, 64);
        if (lane >= o) inc = fminf(inc, u);
    }
    if (lane == 63) wAgg[wid] = inc;
    __syncthreads();

    float wavePrefix = INFINITY;
    for (int i = 0; i < wid; i++) wavePrefix = fminf(wavePrefix, wAgg[i]);
    float excl = __shfl_up(inc, 1, 64);
    if (lane == 0) excl = INFINITY;
    float run = fminf(wavePrefix, excl);

    float sum = 0.0f;
    #pragma unroll
    for (int j = 0; j < 4; j++) {
        run = fminf(run, v[j]);
        if (vl[j]) sum += run;
    }
    #pragma unroll
    for (int o = 32; o; o >>= 1) sum += __shfl_xor(sum, o, 64);
    if (lane == 0) wSum[wid] = sum;
    __syncthreads();
    if (t == 0) {
        float s = 0.0f;
        for (int i = 0; i < 16; i++) s += wSum[i];
        out[0] = s;
    }
}

extern "C" void kernel_launch(void* const* d_in, const int* in_sizes, int n_in,
                              void* d_out, int out_size, void* d_ws, size_t ws_size,
                              hipStream_t stream) {
    const float* verts   = (const float*)d_in[0];
    const float* tab     = (const float*)d_in[1];
    const int*   edges   = (const int*)d_in[2];
    const int*   listAll = (const int*)d_in[3];

    char* ws = (char*)d_ws;
    float4* bk4  = (float4*)ws;                   ws += (size_t)NB * CAP * sizeof(float4); // 2 MB
    float4* tb4  = (float4*)ws;                   ws += NT * sizeof(float4);
    float2* pk2  = (float2*)ws;                   ws += NE * sizeof(float2);
    float*  ea   = (float*)ws;                    ws += NE * sizeof(float);
    float*  eb   = (float*)ws;                    ws += NE * sizeof(float);
    float*  mArr = (float*)ws;                    ws += NP * sizeof(float);
    int*    vArr = (int*)ws;                      ws += NP * sizeof(int);
    int*    cnt  = (int*)ws;

    prep_kernel<<<NB + 5, 1024, 0, stream>>>(verts, edges, tab,
                                             pk2, ea, eb, tb4, bk4, cnt);
    point_kernel<<<NP / 4, 256, 0, stream>>>(verts, listAll, pk2, ea, eb,
                                             bk4, cnt, tb4, mArr, vArr);
    scan_kernel<<<1, 1024, 0, stream>>>(mArr, vArr, (float*)d_out);
}